// Round 5
// baseline (616.719 us; speedup 1.0000x reference)
//
#include <hip/hip_runtime.h>

// Problem constants: B=8, flow (B,2,H,W), depth (B,1,H,W), fp32.
constexpr int B  = 8;
constexpr int H  = 720;
constexpr int W  = 1280;
constexpr int HW = H * W;           // 921600
constexpr int N  = B * HW;          // 7372800

// Tile geometry: each block owns a TY x TX output tile and reads a
// (TY+2C) x (TX+2C) source region. C=6: a source with fx,fy in [-6,6)
// has all 4 corners within Chebyshev distance 6. P(|N(0,1)|>=6) ~ 2e-9.
constexpr int TX = 64;              // 1280 / 64 = 20
constexpr int TY = 48;              // 720  / 48 = 15
constexpr int C  = 6;
constexpr int RW = TX + 2 * C;      // 76
constexpr int RH = TY + 2 * C;      // 60
constexpr int RN = RW * RH;         // 4560
constexpr int TN = TY * TX;         // 3072

// LDS accumulator layout: one array [cnt | ox | oy] so a single byte address
// serves 3 ds_add_f32 via immediate offsets.
constexpr int OX_OFF = TN * 4;      // 12288
constexpr int OY_OFF = 2 * TN * 4;  // 24576
static_assert(OY_OFF < 65536, "DS immediate offset must fit 16 bits");

// Pin the accumulation to native fire-and-forget ds_add_f32. HIP's
// atomicAdd/unsafeAtomicAdd on a generic float* lowered to a flat-aperture
// atomic sequence (evidence: R3==R4 timing byte-identical, zero
// SQ_LDS_BANK_CONFLICT despite ~2M wave-level LDS atomics, 95% idle cycles).
// Low 32 bits of a generic shared pointer = LDS byte offset (flat HW
// requires it); validation would fail loudly if this were wrong.
__device__ __forceinline__ void lds_add3(unsigned addr, float w, float gx, float gy) {
    asm volatile(
        "ds_add_f32 %0, %1\n\t"
        "ds_add_f32 %0, %2 offset:12288\n\t"
        "ds_add_f32 %0, %3 offset:24576"
        :: "v"(addr), "v"(w), "v"(gx), "v"(gy) : "memory");
}

// ---------------------------------------------------------------------------
// Outlier pass: exactly handles the (near-nonexistent) sources whose flow
// falls outside [-C, C). Global atomics into zeroed ws planes.
// ---------------------------------------------------------------------------
__global__ __launch_bounds__(256) void dfp_outlier(
    const float* __restrict__ flow, const float* __restrict__ depth,
    float* __restrict__ pcnt, float* __restrict__ pox, float* __restrict__ poy)
{
    int t = blockIdx.x * 256 + threadIdx.x;
    if (t >= N) return;
    int b = t / HW;
    int p = t - b * HW;
    int i = p / W;
    int j = p - i * W;

    const int fbase = b * 2 * HW;
    float fx = flow[fbase + p];
    float fy = flow[fbase + HW + p];

    // Inliers handled by the tile kernel.
    if (fx >= -(float)C && fx < (float)C && fy >= -(float)C && fy < (float)C) return;

    float x2 = (float)j + fx;
    float y2 = (float)i + fy;
    if (!(x2 >= 0.0f && x2 <= (float)(W - 1) &&
          y2 >= 0.0f && y2 <= (float)(H - 1))) return;   // w = 0 -> no-op

    float d  = depth[t];
    int xL = (int)floorf(x2);
    int yT = (int)floorf(y2);
    int xR = min(xL + 1, W - 1);
    int yB = min(yT + 1, H - 1);
    float w = d, gx = -fx * d, gy = -fy * d;

    float* cb = pcnt + b * HW;
    float* xb = pox  + b * HW;
    float* yb = poy  + b * HW;
    int n00 = yT * W + xL, n01 = yT * W + xR, n10 = yB * W + xL, n11 = yB * W + xR;
    unsafeAtomicAdd(&cb[n00], w); unsafeAtomicAdd(&xb[n00], gx); unsafeAtomicAdd(&yb[n00], gy);
    unsafeAtomicAdd(&cb[n01], w); unsafeAtomicAdd(&xb[n01], gx); unsafeAtomicAdd(&yb[n01], gy);
    unsafeAtomicAdd(&cb[n10], w); unsafeAtomicAdd(&xb[n10], gx); unsafeAtomicAdd(&yb[n10], gy);
    unsafeAtomicAdd(&cb[n11], w); unsafeAtomicAdd(&xb[n11], gx); unsafeAtomicAdd(&yb[n11], gy);
}

// ---------------------------------------------------------------------------
// Tile kernel: LDS-privatized scatter + fused flush/normalize.
// Block owns output tile [ty0, ty0+TY) x [tx0, tx0+TX); reads sources in the
// halo-expanded region; ds_add_f32 contributions landing in its tile (each
// contribution applied exactly once across blocks); then writes normalized
// output directly (adding the outlier planes).
// ---------------------------------------------------------------------------
__global__ __launch_bounds__(256) void dfp_tile(
    const float* __restrict__ flow, const float* __restrict__ depth,
    const float* __restrict__ pcnt, const float* __restrict__ pox,
    const float* __restrict__ poy, float* __restrict__ out)
{
    __shared__ float s_acc[3 * TN];   // [cnt | ox | oy]
    const int tid = threadIdx.x;

    for (int k = tid; k < 3 * TN; k += 256) s_acc[k] = 0.f;
    __syncthreads();

    const unsigned lds_base = (unsigned)(uintptr_t)&s_acc[0];

    const int tx0 = blockIdx.x * TX;
    const int ty0 = blockIdx.y * TY;
    const int b   = blockIdx.z;
    const float* fxp = flow + b * 2 * HW;
    const float* fyp = fxp + HW;
    const float* dp  = depth + b * HW;

    for (int k = tid; k < RN; k += 256) {
        int ry = k / RW;                 // RW=76 const -> magic mul
        int rx = k - ry * RW;
        int gy = ty0 - C + ry;
        int gx = tx0 - C + rx;
        if ((unsigned)gy >= (unsigned)H || (unsigned)gx >= (unsigned)W) continue;
        int g = gy * W + gx;

        float fx = fxp[g];
        float fy = fyp[g];
        // Inlier check (outliers handled by dfp_outlier).
        if (!(fx >= -(float)C && fx < (float)C && fy >= -(float)C && fy < (float)C)) continue;

        float x2 = (float)gx + fx;
        float y2 = (float)gy + fy;
        if (!(x2 >= 0.0f && x2 <= (float)(W - 1) &&
              y2 >= 0.0f && y2 <= (float)(H - 1))) continue;  // w = 0

        float d = dp[g];
        int xL = (int)floorf(x2);
        int yT = (int)floorf(y2);
        int xR = min(xL + 1, W - 1);
        int yB = min(yT + 1, H - 1);
        float w = d, gxv = -fx * d, gyv = -fy * d;

        int lxL = xL - tx0, lxR = xR - tx0;
        int lyT = yT - ty0, lyB = yB - ty0;

        // Clamped corners may coincide -> two adds = multiplicity 2, matching ref.
        if ((unsigned)lyT < TY && (unsigned)lxL < TX)
            lds_add3(lds_base + 4u * (lyT * TX + lxL), w, gxv, gyv);
        if ((unsigned)lyT < TY && (unsigned)lxR < TX)
            lds_add3(lds_base + 4u * (lyT * TX + lxR), w, gxv, gyv);
        if ((unsigned)lyB < TY && (unsigned)lxL < TX)
            lds_add3(lds_base + 4u * (lyB * TX + lxL), w, gxv, gyv);
        if ((unsigned)lyB < TY && (unsigned)lxR < TX)
            lds_add3(lds_base + 4u * (lyB * TX + lxR), w, gxv, gyv);
    }
    __syncthreads();   // implies s_waitcnt lgkmcnt(0) -> all ds_adds visible

    // Fused flush + outlier-plane add + normalize. Lanes cover full 64-wide
    // rows (TX=64) -> coalesced.
    float* outx = out + b * 2 * HW;
    float* outy = outx + HW;
    const float* cb = pcnt + b * HW;
    const float* xb = pox  + b * HW;
    const float* yb = poy  + b * HW;
    for (int k = tid; k < TN; k += 256) {
        int ly = k >> 6;                 // TX = 64
        int lx = k & 63;
        int g = (ty0 + ly) * W + tx0 + lx;
        float c  = s_acc[k]          + cb[g];
        float vx = s_acc[k + TN]     + xb[g];
        float vy = s_acc[k + 2 * TN] + yb[g];
        bool has = c > 0.0f;
        outx[g] = has ? vx / c : 0.0f;
        outy[g] = has ? vy / c : 0.0f;
    }
}

// ---------------------------------------------------------------------------
// Fallback path (Round-2 proven): used only if ws can't hold 3 planes.
// ---------------------------------------------------------------------------
__global__ __launch_bounds__(256) void dfp_scatter(
    const float* __restrict__ flow, const float* __restrict__ depth,
    float* __restrict__ out, float* __restrict__ count)
{
    int t = blockIdx.x * 256 + threadIdx.x;
    if (t >= N) return;
    int b = t / HW;
    int p = t - b * HW;
    int i = p / W;
    int j = p - i * W;
    const int fbase = b * 2 * HW;
    float fx = flow[fbase + p];
    float fy = flow[fbase + HW + p];
    float d  = depth[t];
    float x2 = (float)j + fx;
    float y2 = (float)i + fy;
    if (!(x2 >= 0.0f && x2 <= (float)(W - 1) &&
          y2 >= 0.0f && y2 <= (float)(H - 1))) return;
    int xL = (int)floorf(x2);
    int yT = (int)floorf(y2);
    int xR = min(xL + 1, W - 1);
    int yB = min(yT + 1, H - 1);
    float w = d, gx = -fx * w, gy = -fy * w;
    float* ox = out + fbase;
    float* oy = out + fbase + HW;
    float* cnt = count + b * HW;
    int n00 = yT * W + xL, n01 = yT * W + xR, n10 = yB * W + xL, n11 = yB * W + xR;
    unsafeAtomicAdd(&cnt[n00], w); unsafeAtomicAdd(&ox[n00], gx); unsafeAtomicAdd(&oy[n00], gy);
    unsafeAtomicAdd(&cnt[n01], w); unsafeAtomicAdd(&ox[n01], gx); unsafeAtomicAdd(&oy[n01], gy);
    unsafeAtomicAdd(&cnt[n10], w); unsafeAtomicAdd(&ox[n10], gx); unsafeAtomicAdd(&oy[n10], gy);
    unsafeAtomicAdd(&cnt[n11], w); unsafeAtomicAdd(&ox[n11], gx); unsafeAtomicAdd(&oy[n11], gy);
}

__global__ __launch_bounds__(256) void dfp_normalize(
    float* __restrict__ out, const float* __restrict__ count)
{
    int t = blockIdx.x * 256 + threadIdx.x;
    if (t >= N / 4) return;
    int t4 = t * 4;
    int b  = t4 / HW;
    int p  = t4 - b * HW;
    float4 c = *(const float4*)(count + t4);
    float* ox = out + b * 2 * HW + p;
    float* oy = ox + HW;
    float4 vx = *(const float4*)ox;
    float4 vy = *(const float4*)oy;
    vx.x = (c.x > 0.0f) ? vx.x / c.x : 0.0f;
    vx.y = (c.y > 0.0f) ? vx.y / c.y : 0.0f;
    vx.z = (c.z > 0.0f) ? vx.z / c.z : 0.0f;
    vx.w = (c.w > 0.0f) ? vx.w / c.w : 0.0f;
    vy.x = (c.x > 0.0f) ? vy.x / c.x : 0.0f;
    vy.y = (c.y > 0.0f) ? vy.y / c.y : 0.0f;
    vy.z = (c.z > 0.0f) ? vy.z / c.z : 0.0f;
    vy.w = (c.w > 0.0f) ? vy.w / c.w : 0.0f;
    *(float4*)ox = vx;
    *(float4*)oy = vy;
}

extern "C" void kernel_launch(void* const* d_in, const int* in_sizes, int n_in,
                              void* d_out, int out_size, void* d_ws, size_t ws_size,
                              hipStream_t stream)
{
    const float* flow  = (const float*)d_in[0];
    const float* depth = (const float*)d_in[1];
    float* out = (float*)d_out;

    if (ws_size >= (size_t)3 * N * sizeof(float)) {
        // Fast path: LDS-privatized tile scatter + exact outlier pass.
        float* pcnt = (float*)d_ws;
        float* pox  = pcnt + N;
        float* poy  = pox + N;
        hipMemsetAsync(pcnt, 0, (size_t)3 * N * sizeof(float), stream);
        dfp_outlier<<<(N + 255) / 256, 256, 0, stream>>>(flow, depth, pcnt, pox, poy);
        dim3 grid(W / TX, H / TY, B);   // 20 x 15 x 8 = 2400 blocks
        dfp_tile<<<grid, 256, 0, stream>>>(flow, depth, pcnt, pox, poy, out);
    } else if (ws_size >= (size_t)N * sizeof(float)) {
        // Fallback: proven Round-2 global-atomic path.
        float* count = (float*)d_ws;
        hipMemsetAsync(out,   0, (size_t)2 * N * sizeof(float), stream);
        hipMemsetAsync(count, 0, (size_t)N * sizeof(float),     stream);
        dfp_scatter  <<<(N + 255) / 256,     256, 0, stream>>>(flow, depth, out, count);
        dfp_normalize<<<(N / 4 + 255) / 256, 256, 0, stream>>>(out, count);
    }
    // else: insufficient workspace — cannot run safely.
}

// Round 6
// 394.531 us; speedup vs baseline: 1.5632x; 1.5632x over previous
//
#include <hip/hip_runtime.h>

// Problem constants: B=8, flow (B,2,H,W), depth (B,1,H,W), fp32.
constexpr int B  = 8;
constexpr int H  = 720;
constexpr int W  = 1280;
constexpr int HW = H * W;           // 921600
constexpr int N  = B * HW;          // 7372800

// Gather geometry. Inlier band: fx,fy in [-3,3). An inlier source at sx can
// only touch output columns [sx-3, sx+3] (xL=floor(sx+fx) in [sx-3,sx+2],
// xR=xL+1 clamped; same rows). So output pixel o gathers from sources within
// Chebyshev distance C=3. Outliers (~0.5% for N(0,1) flow) take the exact
// global-atomic path.
constexpr int TX = 64;              // tile cols  (1280/64 = 20)
constexpr int TY = 48;              // tile rows  (720/48  = 15)
constexpr int C  = 3;
constexpr int RW = TX + 2 * C;      // 70 staged cols
constexpr int RH = TY + 2 * C;      // 54 staged rows
constexpr int RN = RW * RH;         // 3780
constexpr int PY = 4;               // output rows per thread per pass
// 256 threads = 64 cols x 4 row-groups; 3 passes cover 48 rows.

// ---------------------------------------------------------------------------
// Outlier pass: sources with fx or fy outside [-3,3). Exact, global atomics
// into zeroed ws planes. ~0.5% of pixels -> ~10 us at measured atomic rate.
// ---------------------------------------------------------------------------
__global__ __launch_bounds__(256) void dfp_outlier(
    const float* __restrict__ flow, const float* __restrict__ depth,
    float* __restrict__ pcnt, float* __restrict__ pox, float* __restrict__ poy)
{
    int t = blockIdx.x * 256 + threadIdx.x;
    if (t >= N) return;
    int b = t / HW;
    int p = t - b * HW;
    int i = p / W;
    int j = p - i * W;

    const int fbase = b * 2 * HW;
    float fx = flow[fbase + p];
    float fy = flow[fbase + HW + p];

    // Inliers handled by the gather kernel. Predicate must match dfp_gather's
    // staging predicate exactly.
    if (fx >= -3.0f && fx < 3.0f && fy >= -3.0f && fy < 3.0f) return;

    float x2 = (float)j + fx;
    float y2 = (float)i + fy;
    if (!(x2 >= 0.0f && x2 <= (float)(W - 1) &&
          y2 >= 0.0f && y2 <= (float)(H - 1))) return;   // w = 0 -> no-op

    float d  = depth[t];
    int xL = (int)floorf(x2);
    int yT = (int)floorf(y2);
    int xR = min(xL + 1, W - 1);
    int yB = min(yT + 1, H - 1);
    float w = d, gx = -fx * d, gy = -fy * d;

    float* cb = pcnt + b * HW;
    float* xb = pox  + b * HW;
    float* yb = poy  + b * HW;
    int n00 = yT * W + xL, n01 = yT * W + xR, n10 = yB * W + xL, n11 = yB * W + xR;
    unsafeAtomicAdd(&cb[n00], w); unsafeAtomicAdd(&xb[n00], gx); unsafeAtomicAdd(&yb[n00], gy);
    unsafeAtomicAdd(&cb[n01], w); unsafeAtomicAdd(&xb[n01], gx); unsafeAtomicAdd(&yb[n01], gy);
    unsafeAtomicAdd(&cb[n10], w); unsafeAtomicAdd(&xb[n10], gx); unsafeAtomicAdd(&yb[n10], gy);
    unsafeAtomicAdd(&cb[n11], w); unsafeAtomicAdd(&xb[n11], gx); unsafeAtomicAdd(&yb[n11], gy);
}

// ---------------------------------------------------------------------------
// Gather kernel: NO atomics. Block owns a 64x48 output tile; stages tile+halo
// sources (flow as float2, depth; outliers/out-of-image zeroed) in LDS; each
// thread accumulates 4 output pixels in registers by scanning the 7x10
// candidate window and testing exact corner matches (clamp multiplicity
// reproduced via mx,my in {0,1,2}); flush adds outlier planes + normalizes.
// ---------------------------------------------------------------------------
__global__ __launch_bounds__(256) void dfp_gather(
    const float* __restrict__ flow, const float* __restrict__ depth,
    const float* __restrict__ pcnt, const float* __restrict__ pox,
    const float* __restrict__ poy, float* __restrict__ out)
{
    __shared__ float2 sfl[RN];   // (fx, fy)
    __shared__ float  sd [RN];   // depth (0 => no contribution)

    const int tid = threadIdx.x;
    const int tx0 = blockIdx.x * TX;
    const int ty0 = blockIdx.y * TY;
    const int b   = blockIdx.z;

    const float* fxp = flow + b * 2 * HW;
    const float* fyp = fxp + HW;
    const float* dp  = depth + b * HW;

    // ---- Stage tile + halo. Out-of-image or outlier -> d = 0 (no-op source).
    for (int k = tid; k < RN; k += 256) {
        int ry = k / RW;                 // const divisor -> magic mul
        int rx = k - ry * RW;
        int gy = ty0 - C + ry;
        int gx = tx0 - C + rx;
        float fx = 0.f, fy = 0.f, d = 0.f;
        if ((unsigned)gy < (unsigned)H && (unsigned)gx < (unsigned)W) {
            int g = gy * W + gx;
            fx = fxp[g];
            fy = fyp[g];
            if (fx >= -3.0f && fx < 3.0f && fy >= -3.0f && fy < 3.0f) {
                d = dp[g];
            } else {
                fx = 0.f; fy = 0.f; d = 0.f;   // outlier: global pass handles it
            }
        }
        sfl[k] = make_float2(fx, fy);
        sd[k]  = d;
    }
    __syncthreads();

    const int ox  = tid & 63;            // tile-local column (0..63)
    const int g0  = tid >> 6;            // row group (0..3)
    const int oxa = tx0 + ox;            // absolute output column

    float* outx = out + b * 2 * HW;
    float* outy = outx + HW;
    const float* cb = pcnt + b * HW;
    const float* xb = pox  + b * HW;
    const float* yb = poy  + b * HW;

    for (int pass = 0; pass < 3; ++pass) {
        const int oy0 = pass * 16 + g0 * PY;   // tile-local first owned row
        const int oyb = ty0 + oy0;             // absolute row of r=0

        float c0 = 0.f, c1 = 0.f, c2 = 0.f, c3 = 0.f;
        float x0 = 0.f, x1 = 0.f, x2a = 0.f, x3 = 0.f;
        float y0 = 0.f, y1 = 0.f, y2a = 0.f, y3 = 0.f;

        for (int dy = -C; dy <= PY - 1 + C; ++dy) {      // 10 rows
            const int   ry      = oy0 + dy + C;          // staged row 0..53
            const int   rowbase = ry * RW;
            const float syf     = (float)(oyb + dy);     // absolute source row
            #pragma unroll
            for (int dx = -C; dx <= C; ++dx) {           // 7 cols
                const int rx = ox + dx + C;              // staged col 0..69
                float2 f = sfl[rowbase + rx];
                float  d = sd [rowbase + rx];

                float sx2 = (float)(oxa + dx) + f.x;
                float sy2 = syf + f.y;
                bool valid = (sx2 >= 0.0f) && (sx2 <= (float)(W - 1)) &&
                             (sy2 >= 0.0f) && (sy2 <= (float)(H - 1));
                float wd = valid ? d : 0.0f;

                int xL = (int)floorf(sx2);
                int xR = min(xL + 1, W - 1);
                int yT = (int)floorf(sy2);
                int yB = min(yT + 1, H - 1);

                float mx = (float)((xL == oxa) + (xR == oxa));   // 0,1,2
                float axc = mx * wd;
                float axx = mx * (-f.x * wd);
                float axy = mx * (-f.y * wd);

                int r0 = yT - oyb;       // row matched by top corner
                int r1 = yB - oyb;       // row matched by bottom corner

                float m0 = (float)((r0 == 0) + (r1 == 0));
                float m1 = (float)((r0 == 1) + (r1 == 1));
                float m2 = (float)((r0 == 2) + (r1 == 2));
                float m3 = (float)((r0 == 3) + (r1 == 3));

                c0 += m0 * axc;  x0  += m0 * axx;  y0  += m0 * axy;
                c1 += m1 * axc;  x1  += m1 * axx;  y1  += m1 * axy;
                c2 += m2 * axc;  x2a += m2 * axx;  y2a += m2 * axy;
                c3 += m3 * axc;  x3  += m3 * axx;  y3  += m3 * axy;
            }
        }

        // ---- Flush: add outlier planes, normalize, write. Coalesced (lane=ox).
        float cc[PY] = {c0, c1, c2, c3};
        float vx[PY] = {x0, x1, x2a, x3};
        float vy[PY] = {y0, y1, y2a, y3};
        #pragma unroll
        for (int r = 0; r < PY; ++r) {
            int ga = (oyb + r) * W + oxa;
            float c  = cc[r] + cb[ga];
            float fx = vx[r] + xb[ga];
            float fy = vy[r] + yb[ga];
            bool has = c > 0.0f;
            outx[ga] = has ? fx / c : 0.0f;
            outy[ga] = has ? fy / c : 0.0f;
        }
    }
}

// ---------------------------------------------------------------------------
// Fallback path (Round-2 proven): used only if ws can't hold 3 planes.
// ---------------------------------------------------------------------------
__global__ __launch_bounds__(256) void dfp_scatter(
    const float* __restrict__ flow, const float* __restrict__ depth,
    float* __restrict__ out, float* __restrict__ count)
{
    int t = blockIdx.x * 256 + threadIdx.x;
    if (t >= N) return;
    int b = t / HW;
    int p = t - b * HW;
    int i = p / W;
    int j = p - i * W;
    const int fbase = b * 2 * HW;
    float fx = flow[fbase + p];
    float fy = flow[fbase + HW + p];
    float d  = depth[t];
    float x2 = (float)j + fx;
    float y2 = (float)i + fy;
    if (!(x2 >= 0.0f && x2 <= (float)(W - 1) &&
          y2 >= 0.0f && y2 <= (float)(H - 1))) return;
    int xL = (int)floorf(x2);
    int yT = (int)floorf(y2);
    int xR = min(xL + 1, W - 1);
    int yB = min(yT + 1, H - 1);
    float w = d, gx = -fx * w, gy = -fy * w;
    float* ox = out + fbase;
    float* oy = out + fbase + HW;
    float* cnt = count + b * HW;
    int n00 = yT * W + xL, n01 = yT * W + xR, n10 = yB * W + xL, n11 = yB * W + xR;
    unsafeAtomicAdd(&cnt[n00], w); unsafeAtomicAdd(&ox[n00], gx); unsafeAtomicAdd(&oy[n00], gy);
    unsafeAtomicAdd(&cnt[n01], w); unsafeAtomicAdd(&ox[n01], gx); unsafeAtomicAdd(&oy[n01], gy);
    unsafeAtomicAdd(&cnt[n10], w); unsafeAtomicAdd(&ox[n10], gx); unsafeAtomicAdd(&oy[n10], gy);
    unsafeAtomicAdd(&cnt[n11], w); unsafeAtomicAdd(&ox[n11], gx); unsafeAtomicAdd(&oy[n11], gy);
}

__global__ __launch_bounds__(256) void dfp_normalize(
    float* __restrict__ out, const float* __restrict__ count)
{
    int t = blockIdx.x * 256 + threadIdx.x;
    if (t >= N / 4) return;
    int t4 = t * 4;
    int b  = t4 / HW;
    int p  = t4 - b * HW;
    float4 c = *(const float4*)(count + t4);
    float* ox = out + b * 2 * HW + p;
    float* oy = ox + HW;
    float4 vx = *(const float4*)ox;
    float4 vy = *(const float4*)oy;
    vx.x = (c.x > 0.0f) ? vx.x / c.x : 0.0f;
    vx.y = (c.y > 0.0f) ? vx.y / c.y : 0.0f;
    vx.z = (c.z > 0.0f) ? vx.z / c.z : 0.0f;
    vx.w = (c.w > 0.0f) ? vx.w / c.w : 0.0f;
    vy.x = (c.x > 0.0f) ? vy.x / c.x : 0.0f;
    vy.y = (c.y > 0.0f) ? vy.y / c.y : 0.0f;
    vy.z = (c.z > 0.0f) ? vy.z / c.z : 0.0f;
    vy.w = (c.w > 0.0f) ? vy.w / c.w : 0.0f;
    *(float4*)ox = vx;
    *(float4*)oy = vy;
}

extern "C" void kernel_launch(void* const* d_in, const int* in_sizes, int n_in,
                              void* d_out, int out_size, void* d_ws, size_t ws_size,
                              hipStream_t stream)
{
    const float* flow  = (const float*)d_in[0];
    const float* depth = (const float*)d_in[1];
    float* out = (float*)d_out;

    if (ws_size >= (size_t)3 * N * sizeof(float)) {
        // Fast path: atomic-free gather + exact outlier pass.
        float* pcnt = (float*)d_ws;
        float* pox  = pcnt + N;
        float* poy  = pox + N;
        hipMemsetAsync(pcnt, 0, (size_t)3 * N * sizeof(float), stream);
        dfp_outlier<<<(N + 255) / 256, 256, 0, stream>>>(flow, depth, pcnt, pox, poy);
        dim3 grid(W / TX, H / TY, B);   // 20 x 15 x 8 = 2400 blocks
        dfp_gather<<<grid, 256, 0, stream>>>(flow, depth, pcnt, pox, poy, out);
    } else if (ws_size >= (size_t)N * sizeof(float)) {
        // Fallback: proven Round-2 global-atomic path.
        float* count = (float*)d_ws;
        hipMemsetAsync(out,   0, (size_t)2 * N * sizeof(float), stream);
        hipMemsetAsync(count, 0, (size_t)N * sizeof(float),     stream);
        dfp_scatter  <<<(N + 255) / 256,     256, 0, stream>>>(flow, depth, out, count);
        dfp_normalize<<<(N / 4 + 255) / 256, 256, 0, stream>>>(out, count);
    }
    // else: insufficient workspace — cannot run safely.
}